// Round 19
// baseline (141.163 us; speedup 1.0000x reference)
//
#include <hip/hip_runtime.h>

typedef unsigned short u16;
typedef __attribute__((ext_vector_type(8))) short s8v;   // 8 x bf16 MFMA A/B frag
typedef __attribute__((ext_vector_type(4))) float f4v;   // MFMA C/D frag

#define B_    2
#define S_    64
#define R_    2048
#define D_    1024
#define H_    16
#define KVH_  4
#define LOG2_10K 13.287712379549449f
// attention scale folded into Q, in exp2 domain: 0.125 * log2(e)
#define QSC_  0.18033688011112042f

__device__ __forceinline__ u16 f2bf(float f) {          // RTNE
  union { float f; unsigned int i; } v; v.f = f;
  unsigned int x = v.i;
  return (u16)((x + 0x7FFFu + ((x >> 16) & 1u)) >> 16);
}
__device__ __forceinline__ u16 f2bf_ru(float f) {       // round-half-up (P only)
  union { float f; unsigned int i; } v; v.f = f;
  return (u16)((v.i + 0x8000u) >> 16);
}
__device__ __forceinline__ float bf2f(u16 u) {
  union { unsigned int i; float f; } v; v.i = ((unsigned int)u) << 16; return v.f;
}

__device__ __forceinline__ f4v mfma2(const s8v& a0, const s8v& a1,
                                     const s8v& b0, const s8v& b1) {
  f4v t = {0.f, 0.f, 0.f, 0.f};
  t = __builtin_amdgcn_mfma_f32_16x16x32_bf16(a0, b0, t, 0, 0, 0);
  t = __builtin_amdgcn_mfma_f32_16x16x32_bf16(a1, b1, t, 0, 0, 0);
  return t;
}

// ---------------------------------------------------------------------------
// Prep: 10 weight transposes + activation convert, ONE launch (z = 0..10).
// ---------------------------------------------------------------------------
struct WT10 { const float* w[10]; u16* o[10]; int C[10]; };

__global__ __launch_bounds__(256)
void transw_k(WT10 ws, const float* __restrict__ xa, const float* __restrict__ xb,
              u16* __restrict__ oa, u16* __restrict__ ob)
{
  const int z = blockIdx.z;
  if (z == 10) {                                 // fused convx slice
    int gid = blockIdx.x + blockIdx.y * 32;      // 0..1023
    #pragma unroll
    for (int it = 0; it < 3; it++) {
      int idx = gid * 256 + threadIdx.x + it * 262144;
      if (idx < 540672) {
        int i = idx * 8;
        const float* src; u16* dst; int off;
        if (i < 131072) { src = xa; dst = oa; off = i; }
        else            { src = xb; dst = ob; off = i - 131072; }
        float4 a = *(const float4*)(src + off);
        float4 b = *(const float4*)(src + off + 4);
        s8v r;
        r[0] = (short)f2bf(a.x); r[1] = (short)f2bf(a.y);
        r[2] = (short)f2bf(a.z); r[3] = (short)f2bf(a.w);
        r[4] = (short)f2bf(b.x); r[5] = (short)f2bf(b.y);
        r[6] = (short)f2bf(b.z); r[7] = (short)f2bf(b.w);
        *(s8v*)(dst + off) = r;
      }
    }
    return;
  }
  const int C = ws.C[z];
  const int c0 = blockIdx.x * 32, k0 = blockIdx.y * 32;
  if (c0 >= C) return;
  __shared__ float t[32][33];
  const float* w = ws.w[z];
  u16* o = ws.o[z];
  const int x = threadIdx.x & 31, y = threadIdx.x >> 5;
  #pragma unroll
  for (int j = 0; j < 4; j++)
    t[y + 8 * j][x] = w[(size_t)(k0 + y + 8 * j) * C + c0 + x];
  __syncthreads();
  #pragma unroll
  for (int j = 0; j < 4; j++)
    o[(size_t)(c0 + y + 8 * j) * 1024 + k0 + x] = f2bf(t[x][y + 8 * j]);
}

// ---------------------------------------------------------------------------
// m97-style GEMM core with global_load_lds(16B) staging (r18 shape).
// ---------------------------------------------------------------------------
__device__ __forceinline__ void gemm_core_gl(
    const u16* __restrict__ Xrow, const u16* __restrict__ WTrow,
    u16* __restrict__ As, u16* __restrict__ Bs, f4v (&acc)[2][4],
    int tid, int l15, int l4, int wro, int wco)
{
  const int w    = tid >> 6;
  const int lane = tid & 63;
  const int rl   = lane >> 3;
  const int c8   = lane & 7;
  const int x7   = l15 & 7;
  const int csw  = (c8 ^ rl) * 8;

  for (int k = 0; k < 16; k++) {
    const int k0 = k * 64;
    __syncthreads();
    #pragma unroll
    for (int j = 0; j < 2; j++) {
      int rbase = w * 16 + j * 8;
      int r = rbase + rl;
      __builtin_amdgcn_global_load_lds(
        (const __attribute__((address_space(1))) void*)(Xrow + (size_t)r * 1024 + k0 + csw),
        (__attribute__((address_space(3))) void*)(As + rbase * 64),
        16, 0, 0);
      __builtin_amdgcn_global_load_lds(
        (const __attribute__((address_space(1))) void*)(WTrow + (size_t)r * 1024 + k0 + csw),
        (__attribute__((address_space(3))) void*)(Bs + rbase * 64),
        16, 0, 0);
    }
    __syncthreads();

    s8v af[2][2], bf4[4][2];
    #pragma unroll
    for (int rc = 0; rc < 2; rc++) {
      int row = wro + rc * 16 + l15;
      af[rc][0] = *(const s8v*)(As + row * 64 + ((l4 ^ x7) * 8));
      af[rc][1] = *(const s8v*)(As + row * 64 + (((l4 + 4) ^ x7) * 8));
    }
    #pragma unroll
    for (int cc = 0; cc < 4; cc++) {
      int row = wco + cc * 16 + l15;
      bf4[cc][0] = *(const s8v*)(Bs + row * 64 + ((l4 ^ x7) * 8));
      bf4[cc][1] = *(const s8v*)(Bs + row * 64 + (((l4 + 4) ^ x7) * 8));
    }
    #pragma unroll
    for (int rc = 0; rc < 2; rc++)
      #pragma unroll
      for (int cc = 0; cc < 4; cc++) {
        acc[rc][cc] = __builtin_amdgcn_mfma_f32_16x16x32_bf16(af[rc][0], bf4[cc][0], acc[rc][cc], 0, 0, 0);
        acc[rc][cc] = __builtin_amdgcn_mfma_f32_16x16x32_bf16(af[rc][1], bf4[cc][1], acc[rc][cc], 0, 0, 0);
      }
  }
  __syncthreads();
}

// Wave epilogue -> LDS staging tile Es[128][136] (bf16, bias+RoPE applied).
__device__ __forceinline__ void epi_to_lds(
    const f4v (&acc)[2][4], const float* __restrict__ Bp, u16* __restrict__ Es,
    int cbr, int wro, int wco, int grb, int LB,
    int ropeMode, bool rope2d, bool sc, int l15, int l4)
{
  float bv[4];
  #pragma unroll
  for (int cc = 0; cc < 4; cc++) bv[cc] = Bp[cbr + cc * 16 + l15];

  if (ropeMode == 0) {
    #pragma unroll
    for (int rc = 0; rc < 2; rc++)
      #pragma unroll
      for (int reg = 0; reg < 4; reg++) {
        int lrow = wro + rc * 16 + l4 * 4 + reg;
        #pragma unroll
        for (int cc = 0; cc < 4; cc++)
          Es[lrow * 136 + wco + cc * 16 + l15] = f2bf(acc[rc][cc][reg] + bv[cc]);
      }
  } else {
    float step = rope2d ? (LOG2_10K / 16.f) : (LOG2_10K / 32.f);
    float inv_lo = exp2f(-(float)l15 * step);
    float inv_hi = rope2d ? inv_lo : inv_lo * exp2f(-16.f * step);
    #pragma unroll
    for (int rc = 0; rc < 2; rc++)
      #pragma unroll
      for (int reg = 0; reg < 4; reg++) {
        int lrow = wro + rc * 16 + l4 * 4 + reg;
        int grow = grb + lrow;
        int pos = grow & (LB - 1);
        int bar = pos >> 5, tib = pos & 31;
        #pragma unroll
        for (int cc = 0; cc < 4; cc++) {
          float inv = (cc & 1) ? inv_hi : inv_lo;
          float bse = rope2d ? (float)((cc & 1) ? tib : bar) : (float)pos;
          float ang = bse * inv;
          float sn, cs;
          sincosf(ang, &sn, &cs);
          float v0 = acc[rc][cc][reg] + bv[cc];
          float v1 = acc[rc][cc ^ 2][reg] + bv[cc ^ 2];
          float rot = (cc < 2) ? -v1 : v1;
          float val = v0 * cs + rot * sn;
          if (sc) val *= QSC_;
          Es[lrow * 136 + wco + cc * 16 + l15] = f2bf(val);
        }
      }
  }
}

__device__ __forceinline__ void store_tile_bf16(
    const u16* __restrict__ Es, u16* __restrict__ out,
    int grb, int c0r, int NH, int LB, int LBS, int tid)
{
  #pragma unroll
  for (int it = 0; it < 4; it++) {
    int idx = it * 512 + tid;
    int r = idx >> 4, ch = idx & 15;
    int grow = grb + r;
    int b = grow >> LBS, pos = grow & (LB - 1);
    int cg = c0r + ch * 8;
    size_t base = (((size_t)b * NH + (cg >> 6)) * LB + pos) * 64 + (cg & 63);
    *(s8v*)(out + base) = *(const s8v*)(Es + r * 136 + ch * 8);
  }
}

__device__ __forceinline__ void store_tile_vT(
    const u16* __restrict__ Es, u16* __restrict__ outT,
    int grb, int kvbase, int LB, int LBS, int tid)
{
  #pragma unroll
  for (int it = 0; it < 4; it++) {
    int idx = tid + it * 512;
    int dcol = idx & 127, rg = idx >> 7;
    int grow = grb + rg * 8;
    int b = grow >> LBS, pos = grow & (LB - 1);
    u16 tmp[8];
    #pragma unroll
    for (int j = 0; j < 8; j++) tmp[j] = Es[(rg * 8 + j) * 136 + dcol];
    u16* dst = outT + (((size_t)(b * KVH_ + kvbase + (dcol >> 6))) * 64 + (dcol & 63)) * LB + pos;
    *(s8v*)dst = *(s8v*)tmp;
  }
}

// ---------------------------------------------------------------------------
// Fused QKV GEMM (summary + regular), XCD-swizzled. grid = 396, block = 512.
// ---------------------------------------------------------------------------
struct QkvA {
  const u16 *X, *WTs, *WTr;
  const float *b0s, *b1s, *b2s, *b0r, *b1r, *b2r;
  u16 *o0s, *o1s, *o2s, *o0r, *o1r, *o2r;
};

__global__ __launch_bounds__(512)
void qkv_k(QkvA a)
{
  int orig = blockIdx.x;
  int xcd = orig & 7, sidx = orig >> 3;
  int wg = (xcd < 4) ? (xcd * 50 + sidx) : (200 + (xcd - 4) * 49 + sidx);
  const int bx = wg % 12, by = wg / 12;
  const bool issum = (by == 0);
  const int c0 = bx * 128;

  __shared__ u16 LDSU[17408];
  u16* As = LDSU;
  u16* Bs = LDSU + 8192;
  u16* Es = LDSU;

  const int tid  = threadIdx.x;
  const int lane = tid & 63;
  const int w    = tid >> 6;
  const int l15  = lane & 15;
  const int l4   = lane >> 4;
  const int wro  = (w >> 1) * 32;
  const int wco  = (w & 1) * 64;

  f4v acc[2][4];
  #pragma unroll
  for (int i = 0; i < 2; i++)
    #pragma unroll
    for (int j = 0; j < 4; j++) acc[i][j] = (f4v){0.f, 0.f, 0.f, 0.f};

  const u16* Xrow  = a.X + (size_t)by * 128 * 1024;
  const u16* WTrow = (issum ? a.WTs : a.WTr) + (size_t)c0 * 1024;
  gemm_core_gl(Xrow, WTrow, As, Bs, acc, tid, l15, l4, wro, wco);

  const int LB  = issum ? 64 : 2048;
  const int LBS = issum ? 6 : 11;
  const int grb = issum ? 0 : (by - 1) * 128;

  if (c0 < 1024) {
    epi_to_lds(acc, issum ? a.b0s : a.b0r, Es, c0 + wco, wro, wco, grb, LB, 1, !issum, true, l15, l4);
    __syncthreads();
    store_tile_bf16(Es, issum ? a.o0s : a.o0r, grb, c0, 16, LB, LBS, tid);
  } else if (c0 < 1280) {
    epi_to_lds(acc, issum ? a.b1s : a.b1r, Es, c0 - 1024 + wco, wro, wco, grb, LB, 1, !issum, false, l15, l4);
    __syncthreads();
    store_tile_bf16(Es, issum ? a.o1s : a.o1r, grb, c0 - 1024, 4, LB, LBS, tid);
  } else {
    epi_to_lds(acc, issum ? a.b2s : a.b2r, Es, c0 - 1280 + wco, wro, wco, grb, LB, 0, false, false, l15, l4);
    __syncthreads();
    store_tile_vT(Es, issum ? a.o2s : a.o2r, grb, (c0 - 1280) >> 6, LB, LBS, tid);
  }
}

// ---------------------------------------------------------------------------
// Phase-1 output GEMM: k2 / v2^T / so. grid = 12, block = 512.
// ---------------------------------------------------------------------------
__global__ __launch_bounds__(512)
void gemm_p1_k(const u16* __restrict__ X, const u16* __restrict__ WT,
               const float* __restrict__ bk2, const float* __restrict__ bv2,
               const float* __restrict__ bso,
               u16* __restrict__ k2, u16* __restrict__ v2T, float* __restrict__ outsum)
{
  const int c0 = blockIdx.x * 128;

  __shared__ u16 LDSU[17408];
  u16* As = LDSU;
  u16* Bs = LDSU + 8192;
  u16* Es = LDSU;

  const int tid  = threadIdx.x;
  const int lane = tid & 63;
  const int w    = tid >> 6;
  const int l15  = lane & 15;
  const int l4   = lane >> 4;
  const int wro  = (w >> 1) * 32;
  const int wco  = (w & 1) * 64;

  f4v acc[2][4];
  #pragma unroll
  for (int i = 0; i < 2; i++)
    #pragma unroll
    for (int j = 0; j < 4; j++) acc[i][j] = (f4v){0.f, 0.f, 0.f, 0.f};

  gemm_core_gl(X, WT + (size_t)c0 * 1024, As, Bs, acc, tid, l15, l4, wro, wco);

  if (c0 < 256) {
    epi_to_lds(acc, bk2, Es, c0 + wco, wro, wco, 0, 64, 0, false, false, l15, l4);
    __syncthreads();
    store_tile_bf16(Es, k2, 0, c0, 4, 64, 6, tid);
  } else if (c0 < 512) {
    epi_to_lds(acc, bv2, Es, c0 - 256 + wco, wro, wco, 0, 64, 0, false, false, l15, l4);
    __syncthreads();
    store_tile_vT(Es, v2T, 0, (c0 - 256) >> 6, 64, 6, tid);
  } else {
    float bv[4];
    #pragma unroll
    for (int cc = 0; cc < 4; cc++) bv[cc] = bso[c0 - 512 + wco + cc * 16 + l15];
    #pragma unroll
    for (int rc = 0; rc < 2; rc++)
      #pragma unroll
      for (int reg = 0; reg < 4; reg++) {
        int row = wro + rc * 16 + l4 * 4 + reg;
        #pragma unroll
        for (int cc = 0; cc < 4; cc++)
          outsum[(size_t)row * 1024 + c0 - 512 + wco + cc * 16 + l15] = acc[rc][cc][reg] + bv[cc];
      }
  }
}

// ---------------------------------------------------------------------------
// ro GEMM. grid = 256, block = 512, XCD-swizzled.
// ---------------------------------------------------------------------------
__global__ __launch_bounds__(512)
void gemm_ro_k(const u16* __restrict__ X, const u16* __restrict__ WT,
               const float* __restrict__ Bp, float* __restrict__ out)
{
  int orig = blockIdx.x;
  int wg = (orig & 7) * 32 + (orig >> 3);
  const int bx = wg & 7, by = wg >> 3;
  const int c0 = bx * 128, r0 = by * 128;

  __shared__ u16 LDSU[16384];
  u16* As = LDSU;
  u16* Bs = LDSU + 8192;

  const int tid  = threadIdx.x;
  const int lane = tid & 63;
  const int w    = tid >> 6;
  const int l15  = lane & 15;
  const int l4   = lane >> 4;
  const int wro  = (w >> 1) * 32;
  const int wco  = (w & 1) * 64;

  f4v acc[2][4];
  #pragma unroll
  for (int i = 0; i < 2; i++)
    #pragma unroll
    for (int j = 0; j < 4; j++) acc[i][j] = (f4v){0.f, 0.f, 0.f, 0.f};

  gemm_core_gl(X + (size_t)r0 * 1024, WT + (size_t)c0 * 1024, As, Bs, acc,
               tid, l15, l4, wro, wco);

  float bv[4];
  #pragma unroll
  for (int cc = 0; cc < 4; cc++) bv[cc] = Bp[c0 + wco + cc * 16 + l15];
  #pragma unroll
  for (int rc = 0; rc < 2; rc++)
    #pragma unroll
    for (int reg = 0; reg < 4; reg++) {
      int row = r0 + wro + rc * 16 + l4 * 4 + reg;
      #pragma unroll
      for (int cc = 0; cc < 4; cc++)
        out[(size_t)row * 1024 + c0 + wco + cc * 16 + l15] = acc[rc][cc][reg] + bv[cc];
    }
}

// ---------------------------------------------------------------------------
// Per-strip softmax (swapped layout: lane owns q = qw + l15, keys in l4/reg).
// ---------------------------------------------------------------------------
template<int PHASE>
__device__ __forceinline__ void strip_sm(
    f4v (&s)[4], float& m, float& lsum, f4v (&acc)[4],
    u16 (&PtS)[16][72], bool need_mask, int kbase, int qrow, int l15, int l4)
{
  float tmax = -1e30f;
  if (need_mask) {
    #pragma unroll
    for (int n = 0; n < 4; n++)
      #pragma unroll
      for (int reg = 0; reg < 4; reg++) {
        int kidx = kbase + n * 16 + l4 * 4 + reg;
        bool ok;
        if (kbase == 0) ok = kidx <= ((PHASE == 1) ? qrow : (qrow >> 5));
        else { int kr = kidx - 64; ok = (PHASE == 1) ? ((kr >> 5) <= qrow) : (kr <= qrow); }
        float sv = ok ? s[n][reg] : -1e30f;
        s[n][reg] = sv;
        tmax = fmaxf(tmax, sv);
      }
  } else {
    #pragma unroll
    for (int n = 0; n < 4; n++)
      #pragma unroll
      for (int reg = 0; reg < 4; reg++) tmax = fmaxf(tmax, s[n][reg]);
  }
  tmax = fmaxf(tmax, __shfl_xor(tmax, 16));
  tmax = fmaxf(tmax, __shfl_xor(tmax, 32));

  if (__any(tmax > m)) {                       // exact rescale-skip
    float mn = fmaxf(m, tmax);
    float f  = __builtin_amdgcn_exp2f(m - mn);
    m = mn;
    lsum *= f;
    #pragma unroll
    for (int dt = 0; dt < 4; dt++)
      #pragma unroll
      for (int reg = 0; reg < 4; reg++) acc[dt][reg] *= f;
  }
  float rsum = 0.f;
  #pragma unroll
  for (int n = 0; n < 4; n++) {
    float p0 = __builtin_amdgcn_exp2f(s[n][0] - m);
    float p1 = __builtin_amdgcn_exp2f(s[n][1] - m);
    float p2 = __builtin_amdgcn_exp2f(s[n][2] - m);
    float p3 = __builtin_amdgcn_exp2f(s[n][3] - m);
    rsum += (p0 + p1) + (p2 + p3);
    uint2 pk;
    pk.x = (unsigned)f2bf_ru(p0) | ((unsigned)f2bf_ru(p1) << 16);
    pk.y = (unsigned)f2bf_ru(p2) | ((unsigned)f2bf_ru(p3) << 16);
    *(uint2*)&PtS[l15][n * 16 + l4 * 4] = pk;
  }
  rsum += __shfl_xor(rsum, 16);
  rsum += __shfl_xor(rsum, 32);
  lsum += rsum;
}

// ---------------------------------------------------------------------------
// Phase 2 attention, split-K with duration-equalized chunks.
// 1024 blocks x 512 thr (8 waves); slot(0..31) x bh(0..31).
// qb 0-4: 1 chunk; qb 5-10: 2 chunks; qb 11-15: 3 chunks (sizes 3..12 tiles).
// Single-buffered K/V (36.9 KB -> 4 blocks/CU = 32 waves/CU nominal).
// Partials: unnormalized O (bf16) + (m, l) fp32, merged by comb2_k.
// ---------------------------------------------------------------------------
__global__ __launch_bounds__(512)
void attn2_k(const u16* __restrict__ Q, const u16* __restrict__ KS,
             const u16* __restrict__ KR, const u16* __restrict__ VST,
             const u16* __restrict__ VRT,
             u16* __restrict__ pO2, float* __restrict__ pml2)
{
  static const int sqb[32] = {0,1,2,3,4,5,5,6,6,7,7,8,8,9,9,10,10,
                              11,11,11,12,12,12,13,13,13,14,14,14,15,15,15};
  static const int sci[32] = {0,0,0,0,0,0,1,0,1,0,1,0,1,0,1,0,1,
                              0,1,2,0,1,2,0,1,2,0,1,2,0,1,2};
  static const int snc[32] = {1,1,1,1,1,2,2,2,2,2,2,2,2,2,2,2,2,
                              3,3,3,3,3,3,3,3,3,3,3,3,3,3,3};
  const int gid  = blockIdx.x;                 // 0..1023
  const int bh   = gid & 31;
  const int slot = gid >> 5;                   // 0..31
  const int qb   = sqb[slot], ci = sci[slot], nch = snc[slot];
  const int nt   = 3 + 2 * qb;
  const int kt0  = (nt * ci) / nch;
  const int kt1  = (nt * (ci + 1)) / nch;
  const int h    = bh & 15, b = bh >> 4;
  const int q0   = qb * 128;
  const int kh   = h >> 2;

  __shared__ u16 Kt[64][72];
  __shared__ u16 Vt[64][72];
  __shared__ u16 Pt[8][16][72];

  const int tid = threadIdx.x, lane = tid & 63, w = tid >> 6;   // w: 0..7
  const int l15 = lane & 15, l4 = lane >> 4;
  const int qw  = q0 + w * 16;

  const u16* qp = Q + (((size_t)b * H_ + h) * R_ + qw + l15) * 64;
  s8v qf0 = *(const s8v*)(qp + l4 * 8);
  s8v qf1 = *(const s8v*)(qp + 32 + l4 * 8);

  f4v acc[4];
  #pragma unroll
  for (int dt = 0; dt < 4; dt++) acc[dt] = (f4v){0.f, 0.f, 0.f, 0.f};
  float m = -1e30f, lsum = 0.f;

  const size_t bh_kv = (size_t)b * KVH_ + kh;
  const int r_ = tid >> 3, sg_ = (tid & 7) * 8;

  // prologue: stage tile kt0 (summary if 0, else regular)
  {
    const u16 *kp, *vp; int vstr;
    if (kt0 == 0) { kp = KS + bh_kv * 4096; vp = VST + bh_kv * 4096; vstr = 64; }
    else {
      kp = KR  + (bh_kv * R_ + kt0 * 64 - 64) * 64;
      vp = VRT + bh_kv * 64 * R_ + (kt0 * 64 - 64);
      vstr = R_;
    }
    s8v kv = *(const s8v*)(kp + r_ * 64 + sg_);
    s8v vv = *(const s8v*)(vp + (size_t)r_ * vstr + sg_);
    *(s8v*)&Kt[r_][sg_] = kv;
    *(s8v*)&Vt[r_][sg_] = vv;
  }
  __syncthreads();

  for (int kt = kt0; kt < kt1; kt++) {
    const int kbase = kt * 64;
    const bool pre = (kt + 1 < kt1);
    s8v knx, vnx;
    if (pre) {                                 // next tile is always regular
      const u16* kp = KR  + (bh_kv * R_ + kbase) * 64;
      const u16* vp = VRT + bh_kv * 64 * R_ + kbase;
      knx = *(const s8v*)(kp + r_ * 64 + sg_);
      vnx = *(const s8v*)(vp + (size_t)r_ * R_ + sg_);
    }

    const bool active = (kbase == 0) || (kbase - 64 <= qw + 15);
    if (active) {
      f4v s[4];
      __builtin_amdgcn_s_setprio(1);
      #pragma unroll
      for (int n = 0; n < 4; n++) {
        s8v kf0 = *(const s8v*)&Kt[n * 16 + l15][l4 * 8];
        s8v kf1 = *(const s8v*)&Kt[n * 16 + l15][32 + l4 * 8];
        s[n] = mfma2(kf0, kf1, qf0, qf1);
      }
      __builtin_amdgcn_s_setprio(0);
      bool nm = (kbase == 0) || ((kbase - 1) > qw);
      strip_sm<2>(s, m, lsum, acc, Pt[w], nm, kbase, qw + l15, l15, l4);
      asm volatile("s_waitcnt lgkmcnt(0)" ::: "memory");
      s8v pf0 = *(const s8v*)&Pt[w][l15][l4 * 8];
      s8v pf1 = *(const s8v*)&Pt[w][l15][32 + l4 * 8];
      __builtin_amdgcn_s_setprio(1);
      #pragma unroll
      for (int dt = 0; dt < 4; dt++) {
        s8v vf0 = *(const s8v*)&Vt[dt * 16 + l15][l4 * 8];
        s8v vf1 = *(const s8v*)&Vt[dt * 16 + l15][32 + l4 * 8];
        acc[dt] = __builtin_amdgcn_mfma_f32_16x16x32_bf16(vf0, pf0, acc[dt], 0, 0, 0);
        acc[dt] = __builtin_amdgcn_mfma_f32_16x16x32_bf16(vf1, pf1, acc[dt], 0, 0, 0);
      }
      __builtin_amdgcn_s_setprio(0);
    }

    __syncthreads();                           // all reads of Kt/Vt done
    if (pre) {
      *(s8v*)&Kt[r_][sg_] = knx;
      *(s8v*)&Vt[r_][sg_] = vnx;
      __syncthreads();                         // writes visible
    }
  }

  // partial epilogue: unnormalized O (bf16) + (m, l)
  const int rowl = w * 16 + l15;
  u16* po = pO2 + (((size_t)slot * 32 + bh) * 128 + rowl) * 64;
  #pragma unroll
  for (int dt = 0; dt < 4; dt++) {
    ushort4 t4;
    t4.x = f2bf(acc[dt][0]);
    t4.y = f2bf(acc[dt][1]);
    t4.z = f2bf(acc[dt][2]);
    t4.w = f2bf(acc[dt][3]);
    *(ushort4*)(po + dt * 16 + l4 * 4) = t4;
  }
  if (l4 == 0) {
    float* pm = pml2 + (((size_t)slot * 32 + bh) * 128 + rowl) * 2;
    pm[0] = m; pm[1] = lsum;
  }
}

// Combine <=3 phase-2 chunks -> rattn bf16 (exp2-domain weights).
__global__ __launch_bounds__(256)
void comb2_k(const u16* __restrict__ pO2, const float* __restrict__ pml2,
             u16* __restrict__ rattn)
{
  static const int SO[16] = {0,1,2,3,4,5,7,9,11,13,15,17,20,23,26,29};
  static const int NC[16] = {1,1,1,1,1,2,2,2,2,2,2,3,3,3,3,3};
  const int t   = blockIdx.x * 256 + threadIdx.x;   // 0..262143
  const int row = t >> 2;                           // 0..65535
  const int dg  = (t & 3) * 16;
  const int q   = row & 2047, bh = row >> 11;
  const int b   = bh >> 4, h = bh & 15;
  const int qb  = q >> 7, rowl = q & 127;
  const int s0  = SO[qb], nc = NC[qb];

  float mv[3], lv[3];
  float mstar = -1e30f;
  #pragma unroll
  for (int ci = 0; ci < 3; ci++) {
    if (ci < nc) {
      const float* p = pml2 + (((size_t)(s0 + ci) * 32 + bh) * 128 + rowl) * 2;
      mv[ci] = p[0]; lv[ci] = p[1];
      mstar = fmaxf(mstar, mv[ci]);
    }
  }
  float o[16];
  #pragma unroll
  for (int j = 0; j < 16; j++) o[j] = 0.f;
  float l = 0.f;
  #pragma unroll
  for (int ci = 0; ci < 3; ci++) {
    if (ci < nc) {
      float wgt = __builtin_amdgcn_exp2f(mv[ci] - mstar);
      l += lv[ci] * wgt;
      const u16* po = pO2 + (((size_t)(s0 + ci) * 32 + bh) * 128 + rowl) * 64 + dg;
      s8v v0 = *(const s8v*)po;
      s8v v1 = *(const s8v*)(po + 8);
      #pragma unroll
      for (int j = 0; j < 8; j++) {
        o[j]     += bf2f((u16)v0[j]) * wgt;
        o[8 + j] += bf2f((u16)v1[j]) * wgt;
      }
    }
  }
  float inv = 1.f / l;
  u16 ob[16];
  #pragma unroll
  for (int j = 0; j < 16; j++) ob[j] = f2bf(o[j] * inv);
  u16* out = rattn + ((size_t)(b * R_ + q)) * D_ + h * 64 + dg;
  *(s8v*)out       = *(s8v*)&ob[0];
  *(s8v*)(out + 8) = *(s8v*)&ob[8];
}

// ---------------------------------------------------------------------------
// Phase 1 attention, split-K (unchanged).
// ---------------------------------------------------------------------------
__global__ __launch_bounds__(256)
void attn1_k(const u16* __restrict__ Q, const u16* __restrict__ KS,
             const u16* __restrict__ KR, const u16* __restrict__ VST,
             const u16* __restrict__ VRT,
             float* __restrict__ pO, float* __restrict__ pml)
{
  const int gid = blockIdx.x;
  const int ck  = gid & 7;
  const int bh  = gid >> 3;
  const int h   = bh & 15, b = bh >> 4;
  const int kh  = h >> 2;
  const int kt0 = (ck * 33) >> 3;
  const int kt1 = ((ck + 1) * 33) >> 3;

  __shared__ u16 Kt[2][64][72];
  __shared__ u16 Vt[2][64][72];
  __shared__ u16 Pt[4][16][72];

  const int tid = threadIdx.x, lane = tid & 63, w = tid >> 6;
  const int l15 = lane & 15, l4 = lane >> 4;
  const int qw  = w * 16;

  const u16* qp = Q + (((size_t)b * H_ + h) * S_ + qw + l15) * 64;
  s8v qf0 = *(const s8v*)(qp + l4 * 8);
  s8v qf1 = *(const s8v*)(qp + 32 + l4 * 8);

  f4v acc[4];
  #pragma unroll
  for (int dt = 0; dt < 4; dt++) acc[dt] = (f4v){0.f, 0.f, 0.f, 0.f};
  float m = -1e30f, lsum = 0.f;

  const size_t bh_kv = (size_t)b * KVH_ + kh;
  const int r_ = tid >> 3, sg_ = (tid & 7) * 8;

  {
    const u16 *kp, *vp; int vstr;
    if (kt0 == 0) { kp = KS + bh_kv * 4096; vp = VST + bh_kv * 4096; vstr = 64; }
    else {
      kp = KR  + (bh_kv * R_ + kt0 * 64 - 64) * 64;
      vp = VRT + bh_kv * 64 * R_ + (kt0 * 64 - 64);
      vstr = R_;
    }
    s8v ka0 = *(const s8v*)(kp + r_ * 64 + sg_);
    s8v ka1 = *(const s8v*)(kp + (r_ + 32) * 64 + sg_);
    s8v va0 = *(const s8v*)(vp + (size_t)r_ * vstr + sg_);
    s8v va1 = *(const s8v*)(vp + (size_t)(r_ + 32) * vstr + sg_);
    *(s8v*)&Kt[0][r_][sg_]      = ka0;
    *(s8v*)&Kt[0][r_ + 32][sg_] = ka1;
    *(s8v*)&Vt[0][r_][sg_]      = va0;
    *(s8v*)&Vt[0][r_ + 32][sg_] = va1;
  }
  __syncthreads();

  for (int kt = kt0; kt < kt1; kt++) {
    const int cur = (kt - kt0) & 1;
    const int kbase = kt * 64;
    const bool pre = (kt + 1 < kt1);
    s8v ka0, ka1, va0, va1;
    if (pre) {
      const u16* kp = KR  + (bh_kv * R_ + kbase) * 64;
      const u16* vp = VRT + bh_kv * 64 * R_ + kbase;
      ka0 = *(const s8v*)(kp + r_ * 64 + sg_);
      ka1 = *(const s8v*)(kp + (r_ + 32) * 64 + sg_);
      va0 = *(const s8v*)(vp + (size_t)r_ * R_ + sg_);
      va1 = *(const s8v*)(vp + (size_t)(r_ + 32) * R_ + sg_);
    }

    const bool active = (kbase == 0) || (((kbase - 64) >> 5) <= qw + 15);
    if (active) {
      f4v s[4];
      __builtin_amdgcn_s_setprio(1);
      #pragma unroll
      for (int n = 0; n < 4; n++) {
        s8v kf0 = *(const s8v*)&Kt[cur][n * 16 + l15][l4 * 8];
        s8v kf1 = *(const s8v*)&Kt[cur][n * 16 + l15][32 + l4 * 8];
        s[n] = mfma2(kf0, kf1, qf0, qf1);
      }
      __builtin_amdgcn_s_setprio(0);
      bool nm = (kbase == 0) || (((kbase - 1) >> 5) > qw);
      strip_sm<1>(s, m, lsum, acc, Pt[w], nm, kbase, qw + l15, l15, l4);
      asm volatile("s_waitcnt lgkmcnt(0)" ::: "memory");
      s8v pf0 = *(const s8v*)&Pt[w][l15][l4 * 8];
      s8v pf1 = *(const s8v*)&Pt[w][l15][32 + l4 * 8];
      __builtin_amdgcn_s_setprio(1);
      #pragma unroll
      for (int dt = 0; dt < 4; dt++) {
        s8v vf0 = *(const s8v*)&Vt[cur][dt * 16 + l15][l4 * 8];
        s8v vf1 = *(const s8v*)&Vt[cur][dt * 16 + l15][32 + l4 * 8];
        acc[dt] = __builtin_amdgcn_mfma_f32_16x16x32_bf16(vf0, pf0, acc[dt], 0, 0, 0);
        acc[dt] = __builtin_amdgcn_mfma_f32_16x16x32_bf16(vf1, pf1, acc[dt], 0, 0, 0);
      }
      __builtin_amdgcn_s_setprio(0);
    }

    if (pre) {
      *(s8v*)&Kt[cur ^ 1][r_][sg_]      = ka0;
      *(s8v*)&Kt[cur ^ 1][r_ + 32][sg_] = ka1;
      *(s8v*)&Vt[cur ^ 1][r_][sg_]      = va0;
      *(s8v*)&Vt[cur ^ 1][r_ + 32][sg_] = va1;
    }
    __syncthreads();
  }

  float* po = pO + (((size_t)ck * 32 + bh) * 64 + qw + l15) * 64;
  #pragma unroll
  for (int dt = 0; dt < 4; dt++)
    *(f4v*)(po + dt * 16 + l4 * 4) = acc[dt];
  if (l4 == 0) {
    float* pm = pml + (((size_t)ck * 32 + bh) * 64 + qw + l15) * 2;
    pm[0] = m; pm[1] = lsum;
  }
}

// Combine 8 phase-1 partials -> sattn bf16 (exp2-domain weights)
__global__ __launch_bounds__(256)
void comb1_k(const float* __restrict__ pO, const float* __restrict__ pml,
             u16* __restrict__ sattn)
{
  const int bh = blockIdx.x;
  const int b = bh >> 4, h = bh & 15;
  const int q  = threadIdx.x >> 2;
  const int d0 = (threadIdx.x & 3) * 16;
  float mv[8], lv[8], mstar = -1e30f;
  #pragma unroll
  for (int c = 0; c < 8; c++) {
    const float* p = pml + (((size_t)c * 32 + bh) * 64 + q) * 2;
    mv[c] = p[0]; lv[c] = p[1];
    mstar = fmaxf(mstar, mv[c]);
  }
  float o[16];
  #pragma unroll
  for (int j = 0; j < 16; j++) o[j] = 0.f;
  float lsum = 0.f;
  #pragma unroll
  for (int c = 0; c < 8; c++) {
    float wgt = __builtin_amdgcn_exp2f(mv[c] - mstar);
    lsum += lv[c] * wgt;
    const float* po = pO + (((size_t)c * 32 + bh) * 64 + q) * 64 + d0;
    #pragma unroll
    for (int j = 0; j < 16; j++) o[j] += po[j] * wgt;
  }
  float inv = 1.f / lsum;
  u16 ob[16];
  #pragma unroll
  for (int j = 0; j < 16; j++) ob[j] = f2bf(o[j] * inv);
  u16* out = sattn + ((size_t)(b * 64 + q)) * 1024 + h * 64 + d0;
  *(s8v*)out       = *(s8v*)&ob[0];
  *(s8v*)(out + 8) = *(s8v*)&ob[8];
}

extern "C" void kernel_launch(void* const* d_in, const int* in_sizes, int n_in,
                              void* d_out, int out_size, void* d_ws, size_t ws_size,
                              hipStream_t stream)
{
  (void)out_size; (void)ws_size;

  static const int expect[22] = {
    131072, 4194304,
    1048576, 1024, 262144, 256,
    262144, 256, 1048576, 1024,
    1048576, 1024, 262144, 256,
    262144, 256, 1048576, 1024,
    262144, 256, 262144, 256
  };
  if (n_in < 22) return;
  for (int i = 0; i < 22; i++) if (in_sizes[i] != expect[i]) return;

  const float* sum_x = (const float*)d_in[0];
  const float* reg_x = (const float*)d_in[1];
  const float* w_sq = (const float*)d_in[2];  const float* b_sq = (const float*)d_in[3];
  const float* w_sk = (const float*)d_in[4];  const float* b_sk = (const float*)d_in[5];
  const float* w_sv = (const float*)d_in[6];  const float* b_sv = (const float*)d_in[7];
  const float* w_so = (const float*)d_in[8];  const float* b_so = (const float*)d_in[9];
  const float* w_rq = (const float*)d_in[10]; const float* b_rq = (const float*)d_in[11];
  const float* w_rk = (const float*)d_in[12]; const float* b_rk = (const float*)d_in[13];
  const float* w_rv = (const float*)d_in[14]; const float* b_rv = (const float*)d_in[15];
  const float* w_ro = (const float*)d_in[16]; const float* b_ro = (const float*)d_in[17];
  const float* w_k2 = (const float*)d_in[18]; const float* b_k2 = (const float*)d_in[19];
  const float* w_v2 = (const float*)d_in[20]; const float* b_v2 = (const float*)d_in[21];

  u16* ws    = (u16*)d_ws;
  u16* xs_bf = ws;                    // 131072
  u16* xr_bf = xs_bf + 131072;        // 4194304
  u16* wt_s  = xr_bf + 4194304;       // 1572864  [sq|sk|sv]
  u16* wt_r  = wt_s  + 1572864;       // 1572864  [rq|rk|rv]
  u16* wt_p  = wt_r  + 1572864;       // 1572864  [k2|v2|so]
  u16* wt_ro = wt_p  + 1572864;       // 1048576
  u16* sq    = wt_ro + 1048576;       // 131072   [B][H][S][64]
  u16* sk    = sq    + 131072;        // 32768    [B][KVH][S][64]
  u16* svT   = sk    + 32768;         // 32768    [B][KVH][64][S]
  u16* rq    = svT   + 32768;         // 4194304  [B][H][R][64]
  u16* rk    = rq    + 4194304;       // 1048576  [B][KVH][R][64]
  u16* rvT   = rk    + 1048576;       // 1048576  [B][KVH][64][R]
  u16* sattn = rvT   + 1048576;       // 131072   [B*S][D]
  u16* k2    = sattn + 131072;        // 32768
  u16* v2T   = k2    + 32768;         // 32768    [B][KVH][64][S]
  u16* rattn = v2T   + 32768;         // 4194304  [B*R][D]

  float* pO  = (float*)rattn;         // phase-1 partials alias rattn (pre-attn2)
  float* pml = pO + 1048576;

  // phase-2 split-K partials alias the dead [xs_bf .. wt_ro) region (18.1 MB):
  // consumed only after qkv (xs/xr/wt_s/wt_r) and gemm_p1 (wt_p) complete.
  float* pml2 = (float*)xs_bf;               // 262144 floats (1 MB)
  u16*   pO2  = xs_bf + 524288;              // 8,388,608 u16 (16.8 MB)

  float* out_sum = (float*)d_out;
  float* out_reg = out_sum + 131072;

  dim3 blk(256);

  WT10 wt;
  wt.w[0] = w_sq; wt.o[0] = wt_s;              wt.C[0] = 1024;
  wt.w[1] = w_rq; wt.o[1] = wt_r;              wt.C[1] = 1024;
  wt.w[2] = w_so; wt.o[2] = wt_p + 512 * 1024; wt.C[2] = 1024;
  wt.w[3] = w_ro; wt.o[3] = wt_ro;             wt.C[3] = 1024;
  wt.w[4] = w_sk; wt.o[4] = wt_s + 1024 * 1024; wt.C[4] = 256;
  wt.w[5] = w_sv; wt.o[5] = wt_s + 1280 * 1024; wt.C[5] = 256;
  wt.w[6] = w_rk; wt.o[6] = wt_r + 1024 * 1024; wt.C[6] = 256;
  wt.w[7] = w_rv; wt.o[7] = wt_r + 1280 * 1024; wt.C[7] = 256;
  wt.w[8] = w_k2; wt.o[8] = wt_p;               wt.C[8] = 256;
  wt.w[9] = w_v2; wt.o[9] = wt_p + 256 * 1024;  wt.C[9] = 256;
  transw_k<<<dim3(32, 32, 11), blk, 0, stream>>>(wt, sum_x, reg_x, xs_bf, xr_bf);

  QkvA qa;
  qa.X = xs_bf; qa.WTs = wt_s; qa.WTr = wt_r;
  qa.b0s = b_sq; qa.b1s = b_sk; qa.b2s = b_sv;
  qa.b0r = b_rq; qa.b1r = b_rk; qa.b2r = b_rv;
  qa.o0s = sq; qa.o1s = sk; qa.o2s = svT;
  qa.o0r = rq; qa.o1r = rk; qa.o2r = rvT;
  qkv_k<<<dim3(396), dim3(512), 0, stream>>>(qa);

  attn1_k<<<dim3(256), blk, 0, stream>>>(sq, sk, rk, svT, rvT, pO, pml);
  comb1_k<<<dim3(32), blk, 0, stream>>>(pO, pml, sattn);

  gemm_p1_k<<<dim3(12), dim3(512), 0, stream>>>(sattn, wt_p, b_k2, b_v2, b_so, k2, v2T, out_sum);

  // phase 2: duration-equalized split-K + combine
  attn2_k<<<dim3(1024), dim3(512), 0, stream>>>(rq, k2, rk, v2T, rvT, pO2, pml2);
  comb2_k<<<dim3(1024), blk, 0, stream>>>(pO2, pml2, rattn);

  gemm_ro_k<<<dim3(256), dim3(512), 0, stream>>>(rattn, wt_ro, b_ro, out_reg);
}

// Round 20
// 129.699 us; speedup vs baseline: 1.0884x; 1.0884x over previous
//
#include <hip/hip_runtime.h>

typedef unsigned short u16;
typedef __attribute__((ext_vector_type(8))) short s8v;   // 8 x bf16 MFMA A/B frag
typedef __attribute__((ext_vector_type(4))) float f4v;   // MFMA C/D frag

#define B_    2
#define S_    64
#define R_    2048
#define D_    1024
#define H_    16
#define KVH_  4
#define LOG2_10K 13.287712379549449f
#define QSC_  0.18033688011112042f   // 0.125 * log2(e): exp2-domain scale in Q

__device__ __forceinline__ u16 f2bf(float f) {          // RTNE
  union { float f; unsigned int i; } v; v.f = f;
  unsigned int x = v.i;
  return (u16)((x + 0x7FFFu + ((x >> 16) & 1u)) >> 16);
}
__device__ __forceinline__ u16 f2bf_ru(float f) {       // round-half-up (P only)
  union { float f; unsigned int i; } v; v.f = f;
  return (u16)((v.i + 0x8000u) >> 16);
}

__device__ __forceinline__ f4v mfma2(const s8v& a0, const s8v& a1,
                                     const s8v& b0, const s8v& b1) {
  f4v t = {0.f, 0.f, 0.f, 0.f};
  t = __builtin_amdgcn_mfma_f32_16x16x32_bf16(a0, b0, t, 0, 0, 0);
  t = __builtin_amdgcn_mfma_f32_16x16x32_bf16(a1, b1, t, 0, 0, 0);
  return t;
}

// ---------------------------------------------------------------------------
// Prep: 10 weight transposes + activation convert, ONE launch (z = 0..10).
// ---------------------------------------------------------------------------
struct WT10 { const float* w[10]; u16* o[10]; int C[10]; };

__global__ __launch_bounds__(256)
void transw_k(WT10 ws, const float* __restrict__ xa, const float* __restrict__ xb,
              u16* __restrict__ oa, u16* __restrict__ ob)
{
  const int z = blockIdx.z;
  if (z == 10) {                                 // fused convx slice
    int gid = blockIdx.x + blockIdx.y * 32;
    #pragma unroll
    for (int it = 0; it < 3; it++) {
      int idx = gid * 256 + threadIdx.x + it * 262144;
      if (idx < 540672) {
        int i = idx * 8;
        const float* src; u16* dst; int off;
        if (i < 131072) { src = xa; dst = oa; off = i; }
        else            { src = xb; dst = ob; off = i - 131072; }
        float4 a = *(const float4*)(src + off);
        float4 b = *(const float4*)(src + off + 4);
        s8v r;
        r[0] = (short)f2bf(a.x); r[1] = (short)f2bf(a.y);
        r[2] = (short)f2bf(a.z); r[3] = (short)f2bf(a.w);
        r[4] = (short)f2bf(b.x); r[5] = (short)f2bf(b.y);
        r[6] = (short)f2bf(b.z); r[7] = (short)f2bf(b.w);
        *(s8v*)(dst + off) = r;
      }
    }
    return;
  }
  const int C = ws.C[z];
  const int c0 = blockIdx.x * 32, k0 = blockIdx.y * 32;
  if (c0 >= C) return;
  __shared__ float t[32][33];
  const float* w = ws.w[z];
  u16* o = ws.o[z];
  const int x = threadIdx.x & 31, y = threadIdx.x >> 5;
  #pragma unroll
  for (int j = 0; j < 4; j++)
    t[y + 8 * j][x] = w[(size_t)(k0 + y + 8 * j) * C + c0 + x];
  __syncthreads();
  #pragma unroll
  for (int j = 0; j < 4; j++)
    o[(size_t)(c0 + y + 8 * j) * 1024 + k0 + x] = f2bf(t[x][y + 8 * j]);
}

// ---------------------------------------------------------------------------
// m97-style GEMM core with global_load_lds(16B) staging (r18 shape).
// ---------------------------------------------------------------------------
__device__ __forceinline__ void gemm_core_gl(
    const u16* __restrict__ Xrow, const u16* __restrict__ WTrow,
    u16* __restrict__ As, u16* __restrict__ Bs, f4v (&acc)[2][4],
    int tid, int l15, int l4, int wro, int wco)
{
  const int w    = tid >> 6;
  const int lane = tid & 63;
  const int rl   = lane >> 3;
  const int c8   = lane & 7;
  const int x7   = l15 & 7;
  const int csw  = (c8 ^ rl) * 8;

  for (int k = 0; k < 16; k++) {
    const int k0 = k * 64;
    __syncthreads();
    #pragma unroll
    for (int j = 0; j < 2; j++) {
      int rbase = w * 16 + j * 8;
      int r = rbase + rl;
      __builtin_amdgcn_global_load_lds(
        (const __attribute__((address_space(1))) void*)(Xrow + (size_t)r * 1024 + k0 + csw),
        (__attribute__((address_space(3))) void*)(As + rbase * 64),
        16, 0, 0);
      __builtin_amdgcn_global_load_lds(
        (const __attribute__((address_space(1))) void*)(WTrow + (size_t)r * 1024 + k0 + csw),
        (__attribute__((address_space(3))) void*)(Bs + rbase * 64),
        16, 0, 0);
    }
    __syncthreads();

    s8v af[2][2], bf4[4][2];
    #pragma unroll
    for (int rc = 0; rc < 2; rc++) {
      int row = wro + rc * 16 + l15;
      af[rc][0] = *(const s8v*)(As + row * 64 + ((l4 ^ x7) * 8));
      af[rc][1] = *(const s8v*)(As + row * 64 + (((l4 + 4) ^ x7) * 8));
    }
    #pragma unroll
    for (int cc = 0; cc < 4; cc++) {
      int row = wco + cc * 16 + l15;
      bf4[cc][0] = *(const s8v*)(Bs + row * 64 + ((l4 ^ x7) * 8));
      bf4[cc][1] = *(const s8v*)(Bs + row * 64 + (((l4 + 4) ^ x7) * 8));
    }
    #pragma unroll
    for (int rc = 0; rc < 2; rc++)
      #pragma unroll
      for (int cc = 0; cc < 4; cc++) {
        acc[rc][cc] = __builtin_amdgcn_mfma_f32_16x16x32_bf16(af[rc][0], bf4[cc][0], acc[rc][cc], 0, 0, 0);
        acc[rc][cc] = __builtin_amdgcn_mfma_f32_16x16x32_bf16(af[rc][1], bf4[cc][1], acc[rc][cc], 0, 0, 0);
      }
  }
  __syncthreads();
}

// Wave epilogue -> LDS staging tile Es[128][136] (bf16, bias+RoPE applied).
__device__ __forceinline__ void epi_to_lds(
    const f4v (&acc)[2][4], const float* __restrict__ Bp, u16* __restrict__ Es,
    int cbr, int wro, int wco, int grb, int LB,
    int ropeMode, bool rope2d, bool sc, int l15, int l4)
{
  float bv[4];
  #pragma unroll
  for (int cc = 0; cc < 4; cc++) bv[cc] = Bp[cbr + cc * 16 + l15];

  if (ropeMode == 0) {
    #pragma unroll
    for (int rc = 0; rc < 2; rc++)
      #pragma unroll
      for (int reg = 0; reg < 4; reg++) {
        int lrow = wro + rc * 16 + l4 * 4 + reg;
        #pragma unroll
        for (int cc = 0; cc < 4; cc++)
          Es[lrow * 136 + wco + cc * 16 + l15] = f2bf(acc[rc][cc][reg] + bv[cc]);
      }
  } else {
    float step = rope2d ? (LOG2_10K / 16.f) : (LOG2_10K / 32.f);
    float inv_lo = exp2f(-(float)l15 * step);
    float inv_hi = rope2d ? inv_lo : inv_lo * exp2f(-16.f * step);
    #pragma unroll
    for (int rc = 0; rc < 2; rc++)
      #pragma unroll
      for (int reg = 0; reg < 4; reg++) {
        int lrow = wro + rc * 16 + l4 * 4 + reg;
        int grow = grb + lrow;
        int pos = grow & (LB - 1);
        int bar = pos >> 5, tib = pos & 31;
        #pragma unroll
        for (int cc = 0; cc < 4; cc++) {
          float inv = (cc & 1) ? inv_hi : inv_lo;
          float bse = rope2d ? (float)((cc & 1) ? tib : bar) : (float)pos;
          float ang = bse * inv;
          float sn, cs;
          sincosf(ang, &sn, &cs);
          float v0 = acc[rc][cc][reg] + bv[cc];
          float v1 = acc[rc][cc ^ 2][reg] + bv[cc ^ 2];
          float rot = (cc < 2) ? -v1 : v1;
          float val = v0 * cs + rot * sn;
          if (sc) val *= QSC_;
          Es[lrow * 136 + wco + cc * 16 + l15] = f2bf(val);
        }
      }
  }
}

__device__ __forceinline__ void store_tile_bf16(
    const u16* __restrict__ Es, u16* __restrict__ out,
    int grb, int c0r, int NH, int LB, int LBS, int tid)
{
  #pragma unroll
  for (int it = 0; it < 4; it++) {
    int idx = it * 512 + tid;
    int r = idx >> 4, ch = idx & 15;
    int grow = grb + r;
    int b = grow >> LBS, pos = grow & (LB - 1);
    int cg = c0r + ch * 8;
    size_t base = (((size_t)b * NH + (cg >> 6)) * LB + pos) * 64 + (cg & 63);
    *(s8v*)(out + base) = *(const s8v*)(Es + r * 136 + ch * 8);
  }
}

__device__ __forceinline__ void store_tile_vT(
    const u16* __restrict__ Es, u16* __restrict__ outT,
    int grb, int kvbase, int LB, int LBS, int tid)
{
  #pragma unroll
  for (int it = 0; it < 4; it++) {
    int idx = tid + it * 512;
    int dcol = idx & 127, rg = idx >> 7;
    int grow = grb + rg * 8;
    int b = grow >> LBS, pos = grow & (LB - 1);
    u16 tmp[8];
    #pragma unroll
    for (int j = 0; j < 8; j++) tmp[j] = Es[(rg * 8 + j) * 136 + dcol];
    u16* dst = outT + (((size_t)(b * KVH_ + kvbase + (dcol >> 6))) * 64 + (dcol & 63)) * LB + pos;
    *(s8v*)dst = *(s8v*)tmp;
  }
}

// ---------------------------------------------------------------------------
// Fused QKV GEMM (summary + regular), XCD-swizzled. grid = 396, block = 512.
// ---------------------------------------------------------------------------
struct QkvA {
  const u16 *X, *WTs, *WTr;
  const float *b0s, *b1s, *b2s, *b0r, *b1r, *b2r;
  u16 *o0s, *o1s, *o2s, *o0r, *o1r, *o2r;
};

__global__ __launch_bounds__(512)
void qkv_k(QkvA a)
{
  int orig = blockIdx.x;
  int xcd = orig & 7, sidx = orig >> 3;
  int wg = (xcd < 4) ? (xcd * 50 + sidx) : (200 + (xcd - 4) * 49 + sidx);
  const int bx = wg % 12, by = wg / 12;
  const bool issum = (by == 0);
  const int c0 = bx * 128;

  __shared__ u16 LDSU[17408];
  u16* As = LDSU;
  u16* Bs = LDSU + 8192;
  u16* Es = LDSU;

  const int tid  = threadIdx.x;
  const int lane = tid & 63;
  const int w    = tid >> 6;
  const int l15  = lane & 15;
  const int l4   = lane >> 4;
  const int wro  = (w >> 1) * 32;
  const int wco  = (w & 1) * 64;

  f4v acc[2][4];
  #pragma unroll
  for (int i = 0; i < 2; i++)
    #pragma unroll
    for (int j = 0; j < 4; j++) acc[i][j] = (f4v){0.f, 0.f, 0.f, 0.f};

  const u16* Xrow  = a.X + (size_t)by * 128 * 1024;
  const u16* WTrow = (issum ? a.WTs : a.WTr) + (size_t)c0 * 1024;
  gemm_core_gl(Xrow, WTrow, As, Bs, acc, tid, l15, l4, wro, wco);

  const int LB  = issum ? 64 : 2048;
  const int LBS = issum ? 6 : 11;
  const int grb = issum ? 0 : (by - 1) * 128;

  if (c0 < 1024) {
    epi_to_lds(acc, issum ? a.b0s : a.b0r, Es, c0 + wco, wro, wco, grb, LB, 1, !issum, true, l15, l4);
    __syncthreads();
    store_tile_bf16(Es, issum ? a.o0s : a.o0r, grb, c0, 16, LB, LBS, tid);
  } else if (c0 < 1280) {
    epi_to_lds(acc, issum ? a.b1s : a.b1r, Es, c0 - 1024 + wco, wro, wco, grb, LB, 1, !issum, false, l15, l4);
    __syncthreads();
    store_tile_bf16(Es, issum ? a.o1s : a.o1r, grb, c0 - 1024, 4, LB, LBS, tid);
  } else {
    epi_to_lds(acc, issum ? a.b2s : a.b2r, Es, c0 - 1280 + wco, wro, wco, grb, LB, 0, false, false, l15, l4);
    __syncthreads();
    store_tile_vT(Es, issum ? a.o2s : a.o2r, grb, (c0 - 1280) >> 6, LB, LBS, tid);
  }
}

// ---------------------------------------------------------------------------
// Phase-1 output GEMM: k2 / v2^T / so. grid = 12, block = 512.
// ---------------------------------------------------------------------------
__global__ __launch_bounds__(512)
void gemm_p1_k(const u16* __restrict__ X, const u16* __restrict__ WT,
               const float* __restrict__ bk2, const float* __restrict__ bv2,
               const float* __restrict__ bso,
               u16* __restrict__ k2, u16* __restrict__ v2T, float* __restrict__ outsum)
{
  const int c0 = blockIdx.x * 128;

  __shared__ u16 LDSU[17408];
  u16* As = LDSU;
  u16* Bs = LDSU + 8192;
  u16* Es = LDSU;

  const int tid  = threadIdx.x;
  const int lane = tid & 63;
  const int w    = tid >> 6;
  const int l15  = lane & 15;
  const int l4   = lane >> 4;
  const int wro  = (w >> 1) * 32;
  const int wco  = (w & 1) * 64;

  f4v acc[2][4];
  #pragma unroll
  for (int i = 0; i < 2; i++)
    #pragma unroll
    for (int j = 0; j < 4; j++) acc[i][j] = (f4v){0.f, 0.f, 0.f, 0.f};

  gemm_core_gl(X, WT + (size_t)c0 * 1024, As, Bs, acc, tid, l15, l4, wro, wco);

  if (c0 < 256) {
    epi_to_lds(acc, bk2, Es, c0 + wco, wro, wco, 0, 64, 0, false, false, l15, l4);
    __syncthreads();
    store_tile_bf16(Es, k2, 0, c0, 4, 64, 6, tid);
  } else if (c0 < 512) {
    epi_to_lds(acc, bv2, Es, c0 - 256 + wco, wro, wco, 0, 64, 0, false, false, l15, l4);
    __syncthreads();
    store_tile_vT(Es, v2T, 0, (c0 - 256) >> 6, 64, 6, tid);
  } else {
    float bv[4];
    #pragma unroll
    for (int cc = 0; cc < 4; cc++) bv[cc] = bso[c0 - 512 + wco + cc * 16 + l15];
    #pragma unroll
    for (int rc = 0; rc < 2; rc++)
      #pragma unroll
      for (int reg = 0; reg < 4; reg++) {
        int row = wro + rc * 16 + l4 * 4 + reg;
        #pragma unroll
        for (int cc = 0; cc < 4; cc++)
          outsum[(size_t)row * 1024 + c0 - 512 + wco + cc * 16 + l15] = acc[rc][cc][reg] + bv[cc];
      }
  }
}

// ---------------------------------------------------------------------------
// ro GEMM. grid = 256, block = 512, XCD-swizzled.
// ---------------------------------------------------------------------------
__global__ __launch_bounds__(512)
void gemm_ro_k(const u16* __restrict__ X, const u16* __restrict__ WT,
               const float* __restrict__ Bp, float* __restrict__ out)
{
  int orig = blockIdx.x;
  int wg = (orig & 7) * 32 + (orig >> 3);
  const int bx = wg & 7, by = wg >> 3;
  const int c0 = bx * 128, r0 = by * 128;

  __shared__ u16 LDSU[16384];
  u16* As = LDSU;
  u16* Bs = LDSU + 8192;

  const int tid  = threadIdx.x;
  const int lane = tid & 63;
  const int w    = tid >> 6;
  const int l15  = lane & 15;
  const int l4   = lane >> 4;
  const int wro  = (w >> 1) * 32;
  const int wco  = (w & 1) * 64;

  f4v acc[2][4];
  #pragma unroll
  for (int i = 0; i < 2; i++)
    #pragma unroll
    for (int j = 0; j < 4; j++) acc[i][j] = (f4v){0.f, 0.f, 0.f, 0.f};

  gemm_core_gl(X + (size_t)r0 * 1024, WT + (size_t)c0 * 1024, As, Bs, acc,
               tid, l15, l4, wro, wco);

  float bv[4];
  #pragma unroll
  for (int cc = 0; cc < 4; cc++) bv[cc] = Bp[c0 + wco + cc * 16 + l15];
  #pragma unroll
  for (int rc = 0; rc < 2; rc++)
    #pragma unroll
    for (int reg = 0; reg < 4; reg++) {
      int row = r0 + wro + rc * 16 + l4 * 4 + reg;
      #pragma unroll
      for (int cc = 0; cc < 4; cc++)
        out[(size_t)row * 1024 + c0 + wco + cc * 16 + l15] = acc[rc][cc][reg] + bv[cc];
    }
}

// ---------------------------------------------------------------------------
// Per-strip softmax, 64-key tile, Pt stride 72 (attn1 only).
// ---------------------------------------------------------------------------
template<int PHASE>
__device__ __forceinline__ void strip_sm(
    f4v (&s)[4], float& m, float& lsum, f4v (&acc)[4],
    u16 (&PtS)[16][72], bool need_mask, int kbase, int qrow, int l15, int l4)
{
  float tmax = -1e30f;
  if (need_mask) {
    #pragma unroll
    for (int n = 0; n < 4; n++)
      #pragma unroll
      for (int reg = 0; reg < 4; reg++) {
        int kidx = kbase + n * 16 + l4 * 4 + reg;
        bool ok;
        if (kbase == 0) ok = kidx <= ((PHASE == 1) ? qrow : (qrow >> 5));
        else { int kr = kidx - 64; ok = (PHASE == 1) ? ((kr >> 5) <= qrow) : (kr <= qrow); }
        float sv = ok ? s[n][reg] : -1e30f;
        s[n][reg] = sv;
        tmax = fmaxf(tmax, sv);
      }
  } else {
    #pragma unroll
    for (int n = 0; n < 4; n++)
      #pragma unroll
      for (int reg = 0; reg < 4; reg++) tmax = fmaxf(tmax, s[n][reg]);
  }
  tmax = fmaxf(tmax, __shfl_xor(tmax, 16));
  tmax = fmaxf(tmax, __shfl_xor(tmax, 32));

  if (__any(tmax > m)) {
    float mn = fmaxf(m, tmax);
    float f  = __builtin_amdgcn_exp2f(m - mn);
    m = mn;
    lsum *= f;
    #pragma unroll
    for (int dt = 0; dt < 4; dt++)
      #pragma unroll
      for (int reg = 0; reg < 4; reg++) acc[dt][reg] *= f;
  }
  float rsum = 0.f;
  #pragma unroll
  for (int n = 0; n < 4; n++) {
    float p0 = __builtin_amdgcn_exp2f(s[n][0] - m);
    float p1 = __builtin_amdgcn_exp2f(s[n][1] - m);
    float p2 = __builtin_amdgcn_exp2f(s[n][2] - m);
    float p3 = __builtin_amdgcn_exp2f(s[n][3] - m);
    rsum += (p0 + p1) + (p2 + p3);
    uint2 pk;
    pk.x = (unsigned)f2bf_ru(p0) | ((unsigned)f2bf_ru(p1) << 16);
    pk.y = (unsigned)f2bf_ru(p2) | ((unsigned)f2bf_ru(p3) << 16);
    *(uint2*)&PtS[l15][n * 16 + l4 * 4] = pk;
  }
  rsum += __shfl_xor(rsum, 16);
  rsum += __shfl_xor(rsum, 32);
  lsum += rsum;
}

// ---------------------------------------------------------------------------
// Phase 2 attention: 512 blocks x 512 thr (8 waves, 128 q/block), 128-key
// MACROTILES. Summary tile (64 keys) first, then exactly qb+1 full 128-key
// regular macrotiles (q0+128 = 128(qb+1)). Halves per-key fixed overhead:
// barrier pairs, reduce-shuffles, rescale occurrences. All waves active on
// all tiles. Complementary qb pairing. LDS 70.7 KB (2 blocks/CU).
// ---------------------------------------------------------------------------
__global__ __launch_bounds__(512)
void attn2_k(const u16* __restrict__ Q, const u16* __restrict__ KS,
             const u16* __restrict__ KR, const u16* __restrict__ VST,
             const u16* __restrict__ VRT, u16* __restrict__ Out)
{
  const int gid = blockIdx.x;
  const int qb  = (gid & 256) ? (15 - (gid & 15)) : (gid & 15);
  const int bh  = gid >> 4;
  const int h   = bh & 15, b = bh >> 4;
  const int q0  = qb * 128;
  const int kh  = h >> 2;

  __shared__ u16 Kt[128][72];     // [key][d]   (summary tile uses rows 0..63)
  __shared__ u16 Vt[64][136];     // [d][key]   (summary tile uses cols 0..63)
  __shared__ u16 Pt[8][16][136];  // per-wave P [q][key], 128 keys + pad

  const int tid = threadIdx.x, lane = tid & 63, w = tid >> 6;   // w: 0..7
  const int l15 = lane & 15, l4 = lane >> 4;
  const int qw  = q0 + w * 16;
  const int qrow = qw + l15;

  const u16* qp = Q + (((size_t)b * H_ + h) * R_ + qrow) * 64;
  s8v qf0 = *(const s8v*)(qp + l4 * 8);
  s8v qf1 = *(const s8v*)(qp + 32 + l4 * 8);

  f4v acc[4];
  #pragma unroll
  for (int dt = 0; dt < 4; dt++) acc[dt] = (f4v){0.f, 0.f, 0.f, 0.f};
  float m = -1e30f, lsum = 0.f;

  const size_t bh_kv = (size_t)b * KVH_ + kh;
  const u16* KRb = KR  + bh_kv * R_ * 64;
  const u16* VRb = VRT + bh_kv * 64 * R_;

  // ---- stage summary tile (64 keys) ----
  {
    const u16* kp = KS  + bh_kv * 4096;
    const u16* vp = VST + bh_kv * 4096;
    int r = tid >> 3, sg = (tid & 7) * 8;
    *(s8v*)&Kt[r][sg] = *(const s8v*)(kp + r * 64 + sg);
    *(s8v*)&Vt[r][sg] = *(const s8v*)(vp + r * 64 + sg);
  }
  __syncthreads();

  // ---- prefetch macrotile 0 into regs (K: 128x64, V: 64x128) ----
  s8v knx[2], vnx[2];
  const int rK = tid >> 3,  cK = (tid & 7) * 8;        // +512: rK2 = rK+64
  const int dV = tid >> 4,  cV = (tid & 15) * 8;       // +512: dV2 = dV+32
  knx[0] = *(const s8v*)(KRb + (size_t)rK * 64 + cK);
  knx[1] = *(const s8v*)(KRb + (size_t)(rK + 64) * 64 + cK);
  vnx[0] = *(const s8v*)(VRb + (size_t)dV * R_ + cV);
  vnx[1] = *(const s8v*)(VRb + (size_t)(dV + 32) * R_ + cV);

  // ---- tile 0: summary (64 keys, always masked) ----
  {
    f4v s[4];
    __builtin_amdgcn_s_setprio(1);
    #pragma unroll
    for (int n = 0; n < 4; n++) {
      s8v kf0 = *(const s8v*)&Kt[n * 16 + l15][l4 * 8];
      s8v kf1 = *(const s8v*)&Kt[n * 16 + l15][32 + l4 * 8];
      s[n] = mfma2(kf0, kf1, qf0, qf1);
    }
    __builtin_amdgcn_s_setprio(0);
    float tmax = -1e30f;
    const int qb5 = qrow >> 5;
    #pragma unroll
    for (int n = 0; n < 4; n++)
      #pragma unroll
      for (int reg = 0; reg < 4; reg++) {
        int kidx = n * 16 + l4 * 4 + reg;
        float sv = (kidx <= qb5) ? s[n][reg] : -1e30f;
        s[n][reg] = sv;
        tmax = fmaxf(tmax, sv);
      }
    tmax = fmaxf(tmax, __shfl_xor(tmax, 16));
    tmax = fmaxf(tmax, __shfl_xor(tmax, 32));
    m = tmax;                                   // first tile: fac irrelevant (acc=0)
    float rsum = 0.f;
    #pragma unroll
    for (int n = 0; n < 4; n++) {
      float p0 = __builtin_amdgcn_exp2f(s[n][0] - m);
      float p1 = __builtin_amdgcn_exp2f(s[n][1] - m);
      float p2 = __builtin_amdgcn_exp2f(s[n][2] - m);
      float p3 = __builtin_amdgcn_exp2f(s[n][3] - m);
      rsum += (p0 + p1) + (p2 + p3);
      uint2 pk;
      pk.x = (unsigned)f2bf_ru(p0) | ((unsigned)f2bf_ru(p1) << 16);
      pk.y = (unsigned)f2bf_ru(p2) | ((unsigned)f2bf_ru(p3) << 16);
      *(uint2*)&Pt[w][l15][n * 16 + l4 * 4] = pk;
    }
    rsum += __shfl_xor(rsum, 16);
    rsum += __shfl_xor(rsum, 32);
    lsum = rsum;
    asm volatile("s_waitcnt lgkmcnt(0)" ::: "memory");
    s8v pf0 = *(const s8v*)&Pt[w][l15][l4 * 8];
    s8v pf1 = *(const s8v*)&Pt[w][l15][32 + l4 * 8];
    __builtin_amdgcn_s_setprio(1);
    #pragma unroll
    for (int dt = 0; dt < 4; dt++) {
      s8v vf0 = *(const s8v*)&Vt[dt * 16 + l15][l4 * 8];
      s8v vf1 = *(const s8v*)&Vt[dt * 16 + l15][32 + l4 * 8];
      acc[dt] = __builtin_amdgcn_mfma_f32_16x16x32_bf16(vf0, pf0, acc[dt], 0, 0, 0);
      acc[dt] = __builtin_amdgcn_mfma_f32_16x16x32_bf16(vf1, pf1, acc[dt], 0, 0, 0);
    }
    __builtin_amdgcn_s_setprio(0);
  }
  __syncthreads();                              // summary K/V reads done
  // write macrotile 0
  *(s8v*)&Kt[rK][cK]      = knx[0];
  *(s8v*)&Kt[rK + 64][cK] = knx[1];
  *(s8v*)&Vt[dV][cV]      = vnx[0];
  *(s8v*)&Vt[dV + 32][cV] = vnx[1];
  __syncthreads();

  // ---- qb+1 full 128-key regular macrotiles ----
  for (int mt = 0; mt <= qb; mt++) {
    const int kstart = mt * 128;
    const bool pre = (mt < qb);
    if (pre) {
      const int ks2 = kstart + 128;
      knx[0] = *(const s8v*)(KRb + (size_t)(ks2 + rK) * 64 + cK);
      knx[1] = *(const s8v*)(KRb + (size_t)(ks2 + rK + 64) * 64 + cK);
      vnx[0] = *(const s8v*)(VRb + (size_t)dV * R_ + ks2 + cV);
      vnx[1] = *(const s8v*)(VRb + (size_t)(dV + 32) * R_ + ks2 + cV);
    }

    f4v s[8];
    __builtin_amdgcn_s_setprio(1);
    #pragma unroll
    for (int n = 0; n < 8; n++) {
      s8v kf0 = *(const s8v*)&Kt[n * 16 + l15][l4 * 8];
      s8v kf1 = *(const s8v*)&Kt[n * 16 + l15][32 + l4 * 8];
      s[n] = mfma2(kf0, kf1, qf0, qf1);
    }
    __builtin_amdgcn_s_setprio(0);

    float tmax = -1e30f;
    if (mt == qb) {                             // only last macrotile masks
      #pragma unroll
      for (int n = 0; n < 8; n++)
        #pragma unroll
        for (int reg = 0; reg < 4; reg++) {
          int kidx = kstart + n * 16 + l4 * 4 + reg;
          float sv = (kidx <= qrow) ? s[n][reg] : -1e30f;
          s[n][reg] = sv;
          tmax = fmaxf(tmax, sv);
        }
    } else {
      #pragma unroll
      for (int n = 0; n < 8; n++)
        #pragma unroll
        for (int reg = 0; reg < 4; reg++) tmax = fmaxf(tmax, s[n][reg]);
    }
    tmax = fmaxf(tmax, __shfl_xor(tmax, 16));
    tmax = fmaxf(tmax, __shfl_xor(tmax, 32));

    if (__any(tmax > m)) {                      // exact rescale-skip
      float mn = fmaxf(m, tmax);
      float f  = __builtin_amdgcn_exp2f(m - mn);
      m = mn;
      lsum *= f;
      #pragma unroll
      for (int dt = 0; dt < 4; dt++)
        #pragma unroll
        for (int reg = 0; reg < 4; reg++) acc[dt][reg] *= f;
    }
    float rsum = 0.f;
    #pragma unroll
    for (int n = 0; n < 8; n++) {
      float p0 = __builtin_amdgcn_exp2f(s[n][0] - m);
      float p1 = __builtin_amdgcn_exp2f(s[n][1] - m);
      float p2 = __builtin_amdgcn_exp2f(s[n][2] - m);
      float p3 = __builtin_amdgcn_exp2f(s[n][3] - m);
      rsum += (p0 + p1) + (p2 + p3);
      uint2 pk;
      pk.x = (unsigned)f2bf_ru(p0) | ((unsigned)f2bf_ru(p1) << 16);
      pk.y = (unsigned)f2bf_ru(p2) | ((unsigned)f2bf_ru(p3) << 16);
      *(uint2*)&Pt[w][l15][n * 16 + l4 * 4] = pk;
    }
    rsum += __shfl_xor(rsum, 16);
    rsum += __shfl_xor(rsum, 32);
    lsum += rsum;

    asm volatile("s_waitcnt lgkmcnt(0)" ::: "memory");

    __builtin_amdgcn_s_setprio(1);
    #pragma unroll
    for (int kb = 0; kb < 4; kb++) {            // 4 x K=32 over the 128 keys
      s8v pf = *(const s8v*)&Pt[w][l15][kb * 32 + l4 * 8];
      #pragma unroll
      for (int dt = 0; dt < 4; dt++) {
        s8v vf = *(const s8v*)&Vt[dt * 16 + l15][kb * 32 + l4 * 8];
        acc[dt] = __builtin_amdgcn_mfma_f32_16x16x32_bf16(vf, pf, acc[dt], 0, 0, 0);
      }
    }
    __builtin_amdgcn_s_setprio(0);

    __syncthreads();                            // all Kt/Vt reads done
    if (pre) {
      *(s8v*)&Kt[rK][cK]      = knx[0];
      *(s8v*)&Kt[rK + 64][cK] = knx[1];
      *(s8v*)&Vt[dV][cV]      = vnx[0];
      *(s8v*)&Vt[dV + 32][cV] = vnx[1];
      __syncthreads();                          // writes visible
    }
  }

  // O^T epilogue: lane owns row q = qrow; 4 x 8B stores cover its 64 d.
  float linv = 1.f / lsum;
  u16* o = Out + ((size_t)b * R_ + qrow) * D_ + h * 64;
  #pragma unroll
  for (int dt = 0; dt < 4; dt++) {
    ushort4 t4;
    t4.x = f2bf(acc[dt][0] * linv);
    t4.y = f2bf(acc[dt][1] * linv);
    t4.z = f2bf(acc[dt][2] * linv);
    t4.w = f2bf(acc[dt][3] * linv);
    *(ushort4*)(o + dt * 16 + l4 * 4) = t4;
  }
}

// ---------------------------------------------------------------------------
// Phase 1 attention, split-K (unchanged).
// ---------------------------------------------------------------------------
__global__ __launch_bounds__(256)
void attn1_k(const u16* __restrict__ Q, const u16* __restrict__ KS,
             const u16* __restrict__ KR, const u16* __restrict__ VST,
             const u16* __restrict__ VRT,
             float* __restrict__ pO, float* __restrict__ pml)
{
  const int gid = blockIdx.x;
  const int ck  = gid & 7;
  const int bh  = gid >> 3;
  const int h   = bh & 15, b = bh >> 4;
  const int kh  = h >> 2;
  const int kt0 = (ck * 33) >> 3;
  const int kt1 = ((ck + 1) * 33) >> 3;

  __shared__ u16 Kt[2][64][72];
  __shared__ u16 Vt[2][64][72];
  __shared__ u16 Pt[4][16][72];

  const int tid = threadIdx.x, lane = tid & 63, w = tid >> 6;
  const int l15 = lane & 15, l4 = lane >> 4;
  const int qw  = w * 16;

  const u16* qp = Q + (((size_t)b * H_ + h) * S_ + qw + l15) * 64;
  s8v qf0 = *(const s8v*)(qp + l4 * 8);
  s8v qf1 = *(const s8v*)(qp + 32 + l4 * 8);

  f4v acc[4];
  #pragma unroll
  for (int dt = 0; dt < 4; dt++) acc[dt] = (f4v){0.f, 0.f, 0.f, 0.f};
  float m = -1e30f, lsum = 0.f;

  const size_t bh_kv = (size_t)b * KVH_ + kh;
  const int r_ = tid >> 3, sg_ = (tid & 7) * 8;

  {
    const u16 *kp, *vp; int vstr;
    if (kt0 == 0) { kp = KS + bh_kv * 4096; vp = VST + bh_kv * 4096; vstr = 64; }
    else {
      kp = KR  + (bh_kv * R_ + kt0 * 64 - 64) * 64;
      vp = VRT + bh_kv * 64 * R_ + (kt0 * 64 - 64);
      vstr = R_;
    }
    s8v ka0 = *(const s8v*)(kp + r_ * 64 + sg_);
    s8v ka1 = *(const s8v*)(kp + (r_ + 32) * 64 + sg_);
    s8v va0 = *(const s8v*)(vp + (size_t)r_ * vstr + sg_);
    s8v va1 = *(const s8v*)(vp + (size_t)(r_ + 32) * vstr + sg_);
    *(s8v*)&Kt[0][r_][sg_]      = ka0;
    *(s8v*)&Kt[0][r_ + 32][sg_] = ka1;
    *(s8v*)&Vt[0][r_][sg_]      = va0;
    *(s8v*)&Vt[0][r_ + 32][sg_] = va1;
  }
  __syncthreads();

  for (int kt = kt0; kt < kt1; kt++) {
    const int cur = (kt - kt0) & 1;
    const int kbase = kt * 64;
    const bool pre = (kt + 1 < kt1);
    s8v ka0, ka1, va0, va1;
    if (pre) {
      const u16* kp = KR  + (bh_kv * R_ + kbase) * 64;
      const u16* vp = VRT + bh_kv * 64 * R_ + kbase;
      ka0 = *(const s8v*)(kp + r_ * 64 + sg_);
      ka1 = *(const s8v*)(kp + (r_ + 32) * 64 + sg_);
      va0 = *(const s8v*)(vp + (size_t)r_ * R_ + sg_);
      va1 = *(const s8v*)(vp + (size_t)(r_ + 32) * R_ + sg_);
    }

    const bool active = (kbase == 0) || (((kbase - 64) >> 5) <= qw + 15);
    if (active) {
      f4v s[4];
      __builtin_amdgcn_s_setprio(1);
      #pragma unroll
      for (int n = 0; n < 4; n++) {
        s8v kf0 = *(const s8v*)&Kt[cur][n * 16 + l15][l4 * 8];
        s8v kf1 = *(const s8v*)&Kt[cur][n * 16 + l15][32 + l4 * 8];
        s[n] = mfma2(kf0, kf1, qf0, qf1);
      }
      __builtin_amdgcn_s_setprio(0);
      bool nm = (kbase == 0) || (((kbase - 1) >> 5) > qw);
      strip_sm<1>(s, m, lsum, acc, Pt[w], nm, kbase, qw + l15, l15, l4);
      asm volatile("s_waitcnt lgkmcnt(0)" ::: "memory");
      s8v pf0 = *(const s8v*)&Pt[w][l15][l4 * 8];
      s8v pf1 = *(const s8v*)&Pt[w][l15][32 + l4 * 8];
      __builtin_amdgcn_s_setprio(1);
      #pragma unroll
      for (int dt = 0; dt < 4; dt++) {
        s8v vf0 = *(const s8v*)&Vt[cur][dt * 16 + l15][l4 * 8];
        s8v vf1 = *(const s8v*)&Vt[cur][dt * 16 + l15][32 + l4 * 8];
        acc[dt] = __builtin_amdgcn_mfma_f32_16x16x32_bf16(vf0, pf0, acc[dt], 0, 0, 0);
        acc[dt] = __builtin_amdgcn_mfma_f32_16x16x32_bf16(vf1, pf1, acc[dt], 0, 0, 0);
      }
      __builtin_amdgcn_s_setprio(0);
    }

    if (pre) {
      *(s8v*)&Kt[cur ^ 1][r_][sg_]      = ka0;
      *(s8v*)&Kt[cur ^ 1][r_ + 32][sg_] = ka1;
      *(s8v*)&Vt[cur ^ 1][r_][sg_]      = va0;
      *(s8v*)&Vt[cur ^ 1][r_ + 32][sg_] = va1;
    }
    __syncthreads();
  }

  float* po = pO + (((size_t)ck * 32 + bh) * 64 + qw + l15) * 64;
  #pragma unroll
  for (int dt = 0; dt < 4; dt++)
    *(f4v*)(po + dt * 16 + l4 * 4) = acc[dt];
  if (l4 == 0) {
    float* pm = pml + (((size_t)ck * 32 + bh) * 64 + qw + l15) * 2;
    pm[0] = m; pm[1] = lsum;
  }
}

// Combine 8 phase-1 partials -> sattn bf16 (exp2-domain weights)
__global__ __launch_bounds__(256)
void comb1_k(const float* __restrict__ pO, const float* __restrict__ pml,
             u16* __restrict__ sattn)
{
  const int bh = blockIdx.x;
  const int b = bh >> 4, h = bh & 15;
  const int q  = threadIdx.x >> 2;
  const int d0 = (threadIdx.x & 3) * 16;
  float mv[8], lv[8], mstar = -1e30f;
  #pragma unroll
  for (int c = 0; c < 8; c++) {
    const float* p = pml + (((size_t)c * 32 + bh) * 64 + q) * 2;
    mv[c] = p[0]; lv[c] = p[1];
    mstar = fmaxf(mstar, mv[c]);
  }
  float o[16];
  #pragma unroll
  for (int j = 0; j < 16; j++) o[j] = 0.f;
  float lsum = 0.f;
  #pragma unroll
  for (int c = 0; c < 8; c++) {
    float wgt = __builtin_amdgcn_exp2f(mv[c] - mstar);
    lsum += lv[c] * wgt;
    const float* po = pO + (((size_t)c * 32 + bh) * 64 + q) * 64 + d0;
    #pragma unroll
    for (int j = 0; j < 16; j++) o[j] += po[j] * wgt;
  }
  float inv = 1.f / lsum;
  u16 ob[16];
  #pragma unroll
  for (int j = 0; j < 16; j++) ob[j] = f2bf(o[j] * inv);
  u16* out = sattn + ((size_t)(b * 64 + q)) * 1024 + h * 64 + d0;
  *(s8v*)out       = *(s8v*)&ob[0];
  *(s8v*)(out + 8) = *(s8v*)&ob[8];
}

extern "C" void kernel_launch(void* const* d_in, const int* in_sizes, int n_in,
                              void* d_out, int out_size, void* d_ws, size_t ws_size,
                              hipStream_t stream)
{
  (void)out_size; (void)ws_size;

  static const int expect[22] = {
    131072, 4194304,
    1048576, 1024, 262144, 256,
    262144, 256, 1048576, 1024,
    1048576, 1024, 262144, 256,
    262144, 256, 1048576, 1024,
    262144, 256, 262144, 256
  };
  if (n_in < 22) return;
  for (int i = 0; i < 22; i++) if (in_sizes[i] != expect[i]) return;

  const float* sum_x = (const float*)d_in[0];
  const float* reg_x = (const float*)d_in[1];
  const float* w_sq = (const float*)d_in[2];  const float* b_sq = (const float*)d_in[3];
  const float* w_sk = (const float*)d_in[4];  const float* b_sk = (const float*)d_in[5];
  const float* w_sv = (const float*)d_in[6];  const float* b_sv = (const float*)d_in[7];
  const float* w_so = (const float*)d_in[8];  const float* b_so = (const float*)d_in[9];
  const float* w_rq = (const float*)d_in[10]; const float* b_rq = (const float*)d_in[11];
  const float* w_rk = (const float*)d_in[12]; const float* b_rk = (const float*)d_in[13];
  const float* w_rv = (const float*)d_in[14]; const float* b_rv = (const float*)d_in[15];
  const float* w_ro = (const float*)d_in[16]; const float* b_ro = (const float*)d_in[17];
  const float* w_k2 = (const float*)d_in[18]; const float* b_k2 = (const float*)d_in[19];
  const float* w_v2 = (const float*)d_in[20]; const float* b_v2 = (const float*)d_in[21];

  u16* ws    = (u16*)d_ws;
  u16* xs_bf = ws;                    // 131072
  u16* xr_bf = xs_bf + 131072;        // 4194304
  u16* wt_s  = xr_bf + 4194304;       // 1572864  [sq|sk|sv]
  u16* wt_r  = wt_s  + 1572864;       // 1572864  [rq|rk|rv]
  u16* wt_p  = wt_r  + 1572864;       // 1572864  [k2|v2|so]
  u16* wt_ro = wt_p  + 1572864;       // 1048576
  u16* sq    = wt_ro + 1048576;       // 131072   [B][H][S][64]
  u16* sk    = sq    + 131072;        // 32768    [B][KVH][S][64]
  u16* svT   = sk    + 32768;         // 32768    [B][KVH][64][S]
  u16* rq    = svT   + 32768;         // 4194304  [B][H][R][64]
  u16* rk    = rq    + 4194304;       // 1048576  [B][KVH][R][64]
  u16* rvT   = rk    + 1048576;       // 1048576  [B][KVH][64][R]
  u16* sattn = rvT   + 1048576;       // 131072   [B*S][D]
  u16* k2    = sattn + 131072;        // 32768
  u16* v2T   = k2    + 32768;         // 32768    [B][KVH][64][S]
  u16* rattn = v2T   + 32768;         // 4194304  [B*R][D]

  float* pO  = (float*)rattn;         // phase-1 partials alias rattn (pre-attn2)
  float* pml = pO + 1048576;

  float* out_sum = (float*)d_out;
  float* out_reg = out_sum + 131072;

  dim3 blk(256);

  WT10 wt;
  wt.w[0] = w_sq; wt.o[0] = wt_s;              wt.C[0] = 1024;
  wt.w[1] = w_rq; wt.o[1] = wt_r;              wt.C[1] = 1024;
  wt.w[2] = w_so; wt.o[2] = wt_p + 512 * 1024; wt.C[2] = 1024;
  wt.w[3] = w_ro; wt.o[3] = wt_ro;             wt.C[3] = 1024;
  wt.w[4] = w_sk; wt.o[4] = wt_s + 1024 * 1024; wt.C[4] = 256;
  wt.w[5] = w_sv; wt.o[5] = wt_s + 1280 * 1024; wt.C[5] = 256;
  wt.w[6] = w_rk; wt.o[6] = wt_r + 1024 * 1024; wt.C[6] = 256;
  wt.w[7] = w_rv; wt.o[7] = wt_r + 1280 * 1024; wt.C[7] = 256;
  wt.w[8] = w_k2; wt.o[8] = wt_p;               wt.C[8] = 256;
  wt.w[9] = w_v2; wt.o[9] = wt_p + 256 * 1024;  wt.C[9] = 256;
  transw_k<<<dim3(32, 32, 11), blk, 0, stream>>>(wt, sum_x, reg_x, xs_bf, xr_bf);

  QkvA qa;
  qa.X = xs_bf; qa.WTs = wt_s; qa.WTr = wt_r;
  qa.b0s = b_sq; qa.b1s = b_sk; qa.b2s = b_sv;
  qa.b0r = b_rq; qa.b1r = b_rk; qa.b2r = b_rv;
  qa.o0s = sq; qa.o1s = sk; qa.o2s = svT;
  qa.o0r = rq; qa.o1r = rk; qa.o2r = rvT;
  qkv_k<<<dim3(396), dim3(512), 0, stream>>>(qa);

  attn1_k<<<dim3(256), blk, 0, stream>>>(sq, sk, rk, svT, rvT, pO, pml);
  comb1_k<<<dim3(32), blk, 0, stream>>>(pO, pml, sattn);

  gemm_p1_k<<<dim3(12), dim3(512), 0, stream>>>(sattn, wt_p, b_k2, b_v2, b_so, k2, v2T, out_sum);

  attn2_k<<<dim3(512), dim3(512), 0, stream>>>(rq, k2, rk, v2T, rvT, rattn);

  gemm_ro_k<<<dim3(256), dim3(512), 0, stream>>>(rattn, wt_ro, b_ro, out_reg);
}